// Round 1
// 2712.093 us; speedup vs baseline: 3.9591x; 3.9591x over previous
//
#include <hip/hip_runtime.h>
#include <math.h>

// N=50000 nodes, E=800000 edges, C=64, R=8, H=64, S=10
// Output row layout (512 floats/node): [mi0:64 | mi1:192 | res0:64 | res1:192]
// h0/h1 (linear_up output) live temporarily in cols 256:512 of d_out; the
// edge phase accumulates T0/T1 into cols 0:256; finalize reads both regions
// then overwrites 256:512 with res.
//
// FAST PATH (needs ~3.6 MB of d_ws): build CSR (dst-sorted edge ids) each
// call, then a node-owned gather kernel accumulates T0/T1 in LDS and writes
// them with plain coalesced stores -- ZERO device-scope float atomics.
// Falls back to the original atomic-scatter kernel if ws is too small.

#define NB 12        // nodes per gather block
#define ACCS 257     // acc row stride (257: bank = (ln*257+idx)%32 spreads ln)

__device__ __forceinline__ float silu(float x) {
    return x / (1.0f + __expf(-x));
}

// ---------------- linear_up: h0 = nf0@Wup0, h1[n,o,i] = sum_c nf1[n,c,i]*Wup1[c,o]
__global__ __launch_bounds__(256) void up_kernel(
    const float* __restrict__ nf0, const float* __restrict__ nf1,
    const float* __restrict__ Wup0, const float* __restrict__ Wup1,
    float* __restrict__ out, int Nn) {
    __shared__ float sW0[4096];
    __shared__ float sW1u[4096];
    __shared__ float s0[4 * 64];
    __shared__ float s1[4 * 192];
    int t = threadIdx.x;
    for (int i = t; i < 4096; i += 256) { sW0[i] = Wup0[i]; sW1u[i] = Wup1[i]; }
    int n0 = blockIdx.x * 4;
    {
        int n = n0 + (t >> 6);
        s0[t] = (n < Nn) ? nf0[(size_t)n * 64 + (t & 63)] : 0.f;
    }
    for (int i = t; i < 768; i += 256) {
        int n = n0 + i / 192;
        s1[i] = (n < Nn) ? nf1[(size_t)n * 192 + (i % 192)] : 0.f;
    }
    __syncthreads();
    int w = t >> 6, o = t & 63;
    int n = n0 + w;
    if (n >= Nn) return;
    float a0 = 0.f, ax = 0.f, ay = 0.f, az = 0.f;
#pragma unroll 8
    for (int c = 0; c < 64; c++) {
        float w0 = sW0[c * 64 + o];
        float w1 = sW1u[c * 64 + o];
        float f0 = s0[w * 64 + c];
        a0 += f0 * w0;
        ax += s1[w * 192 + c * 3 + 0] * w1;
        ay += s1[w * 192 + c * 3 + 1] * w1;
        az += s1[w * 192 + c * 3 + 2] * w1;
    }
    float* row = out + (size_t)n * 512;
    row[256 + o] = a0;
    row[320 + o * 3 + 0] = ax;
    row[320 + o * 3 + 1] = ay;
    row[320 + o * 3 + 2] = az;
}

// ---------------- CSR build: histogram, exclusive scan, fill
__global__ __launch_bounds__(256) void hist_kernel(
    const int* __restrict__ ei, int* __restrict__ cnt, int E) {
    int e = blockIdx.x * 256 + threadIdx.x;
    if (e < E) atomicAdd(&cnt[ei[(size_t)E + e]], 1);
}

__global__ __launch_bounds__(1024) void scan_kernel(
    int* __restrict__ cnt, int* __restrict__ cur, int Nn, int E) {
    __shared__ int wsum[16];
    __shared__ int carry_s;
    int t = threadIdx.x;
    int lane = t & 63, wid = t >> 6;
    if (t == 0) carry_s = 0;
    __syncthreads();
    int nchunk = (Nn + 1023) >> 10;
    for (int ch = 0; ch < nchunk; ch++) {
        int i = (ch << 10) + t;
        int v = (i < Nn) ? cnt[i] : 0;
        int s = v;
#pragma unroll
        for (int d = 1; d < 64; d <<= 1) {
            int u = __shfl_up(s, d);
            if (lane >= d) s += u;
        }
        if (lane == 63) wsum[wid] = s;
        __syncthreads();
        int carry = carry_s;
        if (wid == 0) {
            int x = (lane < 16) ? wsum[lane] : 0;
#pragma unroll
            for (int d = 1; d < 16; d <<= 1) {
                int u = __shfl_up(x, d);
                if (lane >= d) x += u;
            }
            if (lane < 16) wsum[lane] = x;
        }
        __syncthreads();
        int woff = wid ? wsum[wid - 1] : 0;
        int excl = carry + woff + (s - v);
        if (i < Nn) { cnt[i] = excl; cur[i] = excl; }
        __syncthreads();
        if (t == 1023) carry_s = carry + wsum[15];
        __syncthreads();
    }
    if (t == 0) cnt[Nn] = E;
}

__global__ __launch_bounds__(256) void fill_kernel(
    const int* __restrict__ ei, int* __restrict__ cur, int* __restrict__ csr, int E) {
    int e = blockIdx.x * 256 + threadIdx.x;
    if (e < E) {
        int pos = atomicAdd(&cur[ei[(size_t)E + e]], 1);
        csr[pos] = e;
    }
}

// ---------------- node-owned gather: radial-MLP + TP + LDS accumulate + plain store
__global__ __launch_bounds__(256, 2) void gather_kernel(
    const float* __restrict__ edge_feats, const float* __restrict__ edge_attrs1,
    const float* __restrict__ cutoff, const int* __restrict__ ei,
    const int* __restrict__ offs, const int* __restrict__ csr,
    const float* __restrict__ W1g, const float* __restrict__ W2g,
    float* __restrict__ out, int Nn, int E) {
    __shared__ __align__(16) float sW1[8 * 64];       // 2 KB
    __shared__ __align__(16) float sW2[64 * 256];     // 64 KB
    __shared__ float acc[NB * ACCS];                  // 12.05 KB -> 2 blocks/CU
    int t = threadIdx.x;
    sW1[t] = W1g[t];
    sW1[t + 256] = W1g[t + 256];
    {
        float4* d4 = reinterpret_cast<float4*>(sW2);
        const float4* s4 = reinterpret_cast<const float4*>(W2g);
        for (int i = t; i < 4096; i += 256) d4[i] = s4[i];
    }
    for (int i = t; i < NB * ACCS; i += 256) acc[i] = 0.f;
    int n0 = blockIdx.x * NB;
    int nend = n0 + NB; if (nend > Nn) nend = Nn;
    int pbeg = offs[n0];
    int pend = offs[nend];
    __syncthreads();

    const float4* w2v = reinterpret_cast<const float4*>(sW2);
#pragma unroll 1
    for (int p = pbeg + t; p < pend; p += 256) {
        int e = csr[p];
        int src = ei[e];
        int dst = ei[(size_t)E + e];

        float ef[8];
        {
            const float4* pe = reinterpret_cast<const float4*>(edge_feats + (size_t)e * 8);
            float4 a = pe[0], b = pe[1];
            ef[0] = a.x; ef[1] = a.y; ef[2] = a.z; ef[3] = a.w;
            ef[4] = b.x; ef[5] = b.y; ef[6] = b.z; ef[7] = b.w;
        }
        // hidden = silu(ef @ W1)  -- wave-uniform LDS broadcast reads
        float h[64];
#pragma unroll
        for (int hg = 0; hg < 16; hg++) {
            float ax = 0.f, ay = 0.f, az = 0.f, aw = 0.f;
#pragma unroll
            for (int r = 0; r < 8; r++) {
                const float4 wv = *reinterpret_cast<const float4*>(&sW1[r * 64 + hg * 4]);
                ax += ef[r] * wv.x; ay += ef[r] * wv.y;
                az += ef[r] * wv.z; aw += ef[r] * wv.w;
            }
            h[hg * 4 + 0] = silu(ax);
            h[hg * 4 + 1] = silu(ay);
            h[hg * 4 + 2] = silu(az);
            h[hg * 4 + 3] = silu(aw);
        }

        float cut = cutoff[e];
        float sh0 = edge_attrs1[(size_t)e * 3 + 0];
        float sh1v = edge_attrs1[(size_t)e * 3 + 1];
        float sh2 = edge_attrs1[(size_t)e * 3 + 2];
        const float* h0r = out + (size_t)src * 512 + 256;
        const float* h1r = out + (size_t)src * 512 + 320;
        float* ab = acc + (dst - n0) * ACCS;

#pragma unroll 1
        for (int cg = 0; cg < 16; cg++) {
            float a00[4] = {0.f, 0.f, 0.f, 0.f};
            float a11[4] = {0.f, 0.f, 0.f, 0.f};
            float a01[4] = {0.f, 0.f, 0.f, 0.f};
            float a10[4] = {0.f, 0.f, 0.f, 0.f};
#pragma unroll
            for (int l = 0; l < 64; l++) {
                float hl = h[l];
                float4 w00v = w2v[l * 64 + cg];        // wave-uniform b128 broadcast
                float4 w11v = w2v[l * 64 + 16 + cg];
                float4 w01v = w2v[l * 64 + 32 + cg];
                float4 w10v = w2v[l * 64 + 48 + cg];
                a00[0] += hl * w00v.x; a00[1] += hl * w00v.y; a00[2] += hl * w00v.z; a00[3] += hl * w00v.w;
                a11[0] += hl * w11v.x; a11[1] += hl * w11v.y; a11[2] += hl * w11v.z; a11[3] += hl * w11v.w;
                a01[0] += hl * w01v.x; a01[1] += hl * w01v.y; a01[2] += hl * w01v.z; a01[3] += hl * w01v.w;
                a10[0] += hl * w10v.x; a10[1] += hl * w10v.y; a10[2] += hl * w10v.z; a10[3] += hl * w10v.w;
            }
            int c0 = cg * 4;
            float4 h0v = *reinterpret_cast<const float4*>(h0r + c0);
            float4 q0 = *reinterpret_cast<const float4*>(h1r + c0 * 3);
            float4 q1 = *reinterpret_cast<const float4*>(h1r + c0 * 3 + 4);
            float4 q2 = *reinterpret_cast<const float4*>(h1r + c0 * 3 + 8);
            float h0a[4] = {h0v.x, h0v.y, h0v.z, h0v.w};
            float h1a[12] = {q0.x, q0.y, q0.z, q0.w, q1.x, q1.y, q1.z, q1.w,
                             q2.x, q2.y, q2.z, q2.w};
#pragma unroll
            for (int k = 0; k < 4; k++) {
                int c = c0 + k;
                float he0 = h0a[k];
                float e0 = h1a[k * 3 + 0], e1 = h1a[k * 3 + 1], e2 = h1a[k * 3 + 2];
                float d = e0 * sh0 + e1 * sh1v + e2 * sh2;
                float m0 = (a00[k] * he0 + a11[k] * d) * cut;
                atomicAdd(ab + c, m0);                      // ds_add_f32 (LDS)
                float wa = a01[k] * he0 * cut;
                float wb = a10[k] * cut;
                atomicAdd(ab + 64 + c * 3 + 0, wa * sh0 + wb * e0);
                atomicAdd(ab + 64 + c * 3 + 1, wa * sh1v + wb * e1);
                atomicAdd(ab + 64 + c * 3 + 2, wa * sh2 + wb * e2);
            }
        }
    }
    __syncthreads();
    // plain coalesced store of raw T0/T1 (finalize applies 1/16 and Q)
    int nb = nend - n0;
    for (int i = t; i < nb * 256; i += 256) {
        int ln = i >> 8, idx = i & 255;
        out[(size_t)(n0 + ln) * 512 + idx] = acc[ln * ACCS + idx];
    }
}

// ---------------- FALLBACK: original fused atomic-scatter edge kernel
__global__ __launch_bounds__(256, 2) void edge_kernel(
    const float* __restrict__ edge_feats, const float* __restrict__ edge_attrs1,
    const float* __restrict__ cutoff, const int* __restrict__ edge_index,
    const float* __restrict__ W1g, const float* __restrict__ W2g,
    float* __restrict__ out, int E) {
    __shared__ __align__(16) float sW1[8 * 64];
    __shared__ __align__(16) float sW2[64 * 256];
    int t = threadIdx.x;
    sW1[t] = W1g[t];
    sW1[t + 256] = W1g[t + 256];
    for (int i = t; i < 16384; i += 256) sW2[i] = W2g[i];
    __syncthreads();

    int e = blockIdx.x * 256 + t;
    if (e >= E) return;

    float ef[8];
    {
        const float4* p = reinterpret_cast<const float4*>(edge_feats + (size_t)e * 8);
        float4 a = p[0], b = p[1];
        ef[0] = a.x; ef[1] = a.y; ef[2] = a.z; ef[3] = a.w;
        ef[4] = b.x; ef[5] = b.y; ef[6] = b.z; ef[7] = b.w;
    }
    float h[64];
#pragma unroll
    for (int hg = 0; hg < 16; hg++) {
        float ax = 0.f, ay = 0.f, az = 0.f, aw = 0.f;
#pragma unroll
        for (int r = 0; r < 8; r++) {
            const float4 wv = *reinterpret_cast<const float4*>(&sW1[r * 64 + hg * 4]);
            ax += ef[r] * wv.x; ay += ef[r] * wv.y;
            az += ef[r] * wv.z; aw += ef[r] * wv.w;
        }
        h[hg * 4 + 0] = silu(ax);
        h[hg * 4 + 1] = silu(ay);
        h[hg * 4 + 2] = silu(az);
        h[hg * 4 + 3] = silu(aw);
    }

    int src = edge_index[e];
    int dst = edge_index[(size_t)E + e];
    float cut = cutoff[e];
    float sh0 = edge_attrs1[(size_t)e * 3 + 0];
    float sh1v = edge_attrs1[(size_t)e * 3 + 1];
    float sh2 = edge_attrs1[(size_t)e * 3 + 2];
    const float* h0r = out + (size_t)src * 512 + 256;
    const float* h1r = out + (size_t)src * 512 + 320;
    float* outr = out + (size_t)dst * 512;
    const float4* w2v = reinterpret_cast<const float4*>(sW2);

#pragma unroll 1
    for (int cg = 0; cg < 16; cg++) {
        float a00[4] = {0.f, 0.f, 0.f, 0.f};
        float a11[4] = {0.f, 0.f, 0.f, 0.f};
        float a01[4] = {0.f, 0.f, 0.f, 0.f};
        float a10[4] = {0.f, 0.f, 0.f, 0.f};
#pragma unroll
        for (int l = 0; l < 64; l++) {
            float hl = h[l];
            float4 w00v = w2v[l * 64 + cg];
            float4 w11v = w2v[l * 64 + 16 + cg];
            float4 w01v = w2v[l * 64 + 32 + cg];
            float4 w10v = w2v[l * 64 + 48 + cg];
            a00[0] += hl * w00v.x; a00[1] += hl * w00v.y; a00[2] += hl * w00v.z; a00[3] += hl * w00v.w;
            a11[0] += hl * w11v.x; a11[1] += hl * w11v.y; a11[2] += hl * w11v.z; a11[3] += hl * w11v.w;
            a01[0] += hl * w01v.x; a01[1] += hl * w01v.y; a01[2] += hl * w01v.z; a01[3] += hl * w01v.w;
            a10[0] += hl * w10v.x; a10[1] += hl * w10v.y; a10[2] += hl * w10v.z; a10[3] += hl * w10v.w;
        }
        int c0 = cg * 4;
        float4 h0v = *reinterpret_cast<const float4*>(h0r + c0);
        float4 q0 = *reinterpret_cast<const float4*>(h1r + c0 * 3);
        float4 q1 = *reinterpret_cast<const float4*>(h1r + c0 * 3 + 4);
        float4 q2 = *reinterpret_cast<const float4*>(h1r + c0 * 3 + 8);
        float h0a[4] = {h0v.x, h0v.y, h0v.z, h0v.w};
        float h1a[12] = {q0.x, q0.y, q0.z, q0.w, q1.x, q1.y, q1.z, q1.w,
                         q2.x, q2.y, q2.z, q2.w};
#pragma unroll
        for (int k = 0; k < 4; k++) {
            int c = c0 + k;
            float he0 = h0a[k];
            float e0 = h1a[k * 3 + 0], e1 = h1a[k * 3 + 1], e2 = h1a[k * 3 + 2];
            float d = e0 * sh0 + e1 * sh1v + e2 * sh2;
            float m0 = (a00[k] * he0 + a11[k] * d) * cut;
            atomicAdd(outr + c, m0);
            float wa = a01[k] * he0 * cut;
            float wb = a10[k] * cut;
            atomicAdd(outr + 64 + c * 3 + 0, wa * sh0 + wb * e0);
            atomicAdd(outr + 64 + c * 3 + 1, wa * sh1v + wb * e1);
            atomicAdd(outr + 64 + c * 3 + 2, wa * sh2 + wb * e2);
        }
    }
}

// ---------------- finalize: scale by 1/16, apply Q0/Q1, species residual
__global__ __launch_bounds__(256) void finalize_kernel(
    const float* __restrict__ node_attrs, const float* __restrict__ Wsc0,
    const float* __restrict__ Wsc1, const float* __restrict__ Q0,
    const float* __restrict__ Q1, float* __restrict__ out, int Nn) {
    __shared__ float smi0[4][64];
    __shared__ float smi1[4][192];
    int t = threadIdx.x;
    int w = t >> 6, o = t & 63;
    int n = blockIdx.x * 4 + w;
    const float inv = 1.0f / 16.0f;
    float q00 = Q0[0];
    float Q[9];
#pragma unroll
    for (int i = 0; i < 9; i++) Q[i] = Q1[i];
    if (n < Nn) {
        float* row = out + (size_t)n * 512;
        float t0 = row[o];
        float ta = row[64 + o * 3 + 0];
        float tb = row[64 + o * 3 + 1];
        float tc = row[64 + o * 3 + 2];
        float mi0 = t0 * inv * q00;
        float m0i = inv * (ta * Q[0] + tb * Q[3] + tc * Q[6]);
        float m1i = inv * (ta * Q[1] + tb * Q[4] + tc * Q[7]);
        float m2i = inv * (ta * Q[2] + tb * Q[5] + tc * Q[8]);
        row[o] = mi0;
        row[64 + o * 3 + 0] = m0i;
        row[64 + o * 3 + 1] = m1i;
        row[64 + o * 3 + 2] = m2i;
        smi0[w][o] = mi0;
        smi1[w][o * 3 + 0] = m0i;
        smi1[w][o * 3 + 1] = m1i;
        smi1[w][o * 3 + 2] = m2i;
    }
    __syncthreads();
    if (n >= Nn) return;
    float acc0 = 0.f, acc1x = 0.f, acc1y = 0.f, acc1z = 0.f;
    for (int s = 0; s < 10; s++) {
        float a = node_attrs[(size_t)n * 10 + s];
        if (a != 0.f) {
            const float* w0 = Wsc0 + s * 4096;
            const float* w1 = Wsc1 + s * 4096;
            float p0 = 0.f, px = 0.f, py = 0.f, pz = 0.f;
#pragma unroll 8
            for (int c = 0; c < 64; c++) {
                float v0 = w0[c * 64 + o];
                float v1 = w1[c * 64 + o];
                p0 += smi0[w][c] * v0;
                px += smi1[w][c * 3 + 0] * v1;
                py += smi1[w][c * 3 + 1] * v1;
                pz += smi1[w][c * 3 + 2] * v1;
            }
            acc0 += a * p0; acc1x += a * px; acc1y += a * py; acc1z += a * pz;
        }
    }
    float* row = out + (size_t)n * 512;
    row[256 + o] = acc0;
    row[320 + o * 3 + 0] = acc1x;
    row[320 + o * 3 + 1] = acc1y;
    row[320 + o * 3 + 2] = acc1z;
}

extern "C" void kernel_launch(void* const* d_in, const int* in_sizes, int n_in,
                              void* d_out, int out_size, void* d_ws, size_t ws_size,
                              hipStream_t stream) {
    const float* nf0   = (const float*)d_in[0];
    const float* nf1   = (const float*)d_in[1];
    const float* attrs = (const float*)d_in[2];
    const float* ef    = (const float*)d_in[3];
    const float* ea1   = (const float*)d_in[4];
    const float* cut   = (const float*)d_in[5];
    const float* Wup0  = (const float*)d_in[6];
    const float* Wup1  = (const float*)d_in[7];
    const float* W1    = (const float*)d_in[8];
    const float* W2    = (const float*)d_in[9];
    const float* Wsc0  = (const float*)d_in[10];
    const float* Wsc1  = (const float*)d_in[11];
    const float* Q0    = (const float*)d_in[12];
    const float* Q1    = (const float*)d_in[13];
    const int*   ei    = (const int*)d_in[14];
    int Nn = in_sizes[0] / 64;      // 50000
    int E  = in_sizes[14] / 2;      // 800000
    float* out = (float*)d_out;

    // ws layout (ints): cnt/offs [Nn+1] | cur [Nn] | csr [E]
    size_t need_bytes = ((size_t)(2 * Nn + 1) + (size_t)E) * sizeof(int);
    int ebl = (E + 255) / 256;

    if (d_ws != nullptr && ws_size >= need_bytes) {
        int* cnt = (int*)d_ws;
        int* cur = cnt + (Nn + 1);
        int* csr = cur + Nn;
        hipMemsetAsync(cnt, 0, (size_t)(Nn + 1) * sizeof(int), stream);
        hist_kernel<<<ebl, 256, 0, stream>>>(ei, cnt, E);
        scan_kernel<<<1, 1024, 0, stream>>>(cnt, cur, Nn, E);
        fill_kernel<<<ebl, 256, 0, stream>>>(ei, cur, csr, E);
        up_kernel<<<(Nn + 3) / 4, 256, 0, stream>>>(nf0, nf1, Wup0, Wup1, out, Nn);
        gather_kernel<<<(Nn + NB - 1) / NB, 256, 0, stream>>>(
            ef, ea1, cut, ei, cnt, csr, W1, W2, out, Nn, E);
        finalize_kernel<<<(Nn + 3) / 4, 256, 0, stream>>>(attrs, Wsc0, Wsc1, Q0, Q1, out, Nn);
    } else {
        // fallback: original atomic-scatter path (out must be zeroed)
        hipMemsetAsync(out, 0, (size_t)out_size * sizeof(float), stream);
        up_kernel<<<(Nn + 3) / 4, 256, 0, stream>>>(nf0, nf1, Wup0, Wup1, out, Nn);
        edge_kernel<<<ebl, 256, 0, stream>>>(ef, ea1, cut, ei, W1, W2, out, E);
        finalize_kernel<<<(Nn + 3) / 4, 256, 0, stream>>>(attrs, Wsc0, Wsc1, Q0, Q1, out, Nn);
    }
}